// Round 3
// baseline (504.137 us; speedup 1.0000x reference)
//
#include <hip/hip_runtime.h>
#include <hip/hip_bf16.h>
#include <float.h>
#include <math.h>

typedef float v4f __attribute__((ext_vector_type(4)));  // native vector: OK for nontemporal builtins

// Kernel 1: mean of edge_vector (n=128 floats) -> d_ws[0].
// One wave (64 lanes), each lane sums n/64 elements, butterfly shuffle reduce.
__global__ void ee_mean_kernel(const float* __restrict__ ev,
                               float* __restrict__ out_mean, int n) {
    int lane = threadIdx.x;  // blockDim.x == 64
    float s = 0.0f;
    for (int i = lane; i < n; i += 64) s += ev[i];
    #pragma unroll
    for (int off = 32; off > 0; off >>= 1) s += __shfl_down(s, off, 64);
    if (lane == 0) out_mean[0] = s / (float)n;
}

// nan_to_num semantics of jnp: NaN->0, +inf->FLT_MAX, -inf->-FLT_MAX
__device__ __forceinline__ float nan_to_num_f(float x) {
    if (isnan(x)) return 0.0f;
    if (isinf(x)) return x > 0.0f ? FLT_MAX : -FLT_MAX;
    return x;
}

__device__ __forceinline__ float ee_elem(float w, float m) {
    // jnp.minimum propagates NaN; NaN * m = NaN; nan_to_num -> 0.
    if (isnan(w)) return 0.0f;
    float v = fminf(w, 5.0f);  // MAX_PATH_DISTANCE
    return nan_to_num_f(v * m);
}

// Kernel 2: out[i] = nan_to_num(min(w[i],5) * mean), 16B-vectorized,
// grid-stride (memory-bound; 2048 blocks, nontemporal store for streamed output).
__global__ void EdgeEncoding_57655640982216_kernel(
    const float* __restrict__ w, const float* __restrict__ mean_p,
    float* __restrict__ out, long long n4) {
    const float m = *mean_p;  // L2-broadcast scalar
    const v4f* __restrict__ w4 = (const v4f*)w;
    v4f* __restrict__ o4 = (v4f*)out;
    long long stride = (long long)gridDim.x * blockDim.x;
    for (long long i = (long long)blockIdx.x * blockDim.x + threadIdx.x;
         i < n4; i += stride) {
        v4f v = w4[i];
        v4f r;
        r.x = ee_elem(v.x, m);
        r.y = ee_elem(v.y, m);
        r.z = ee_elem(v.z, m);
        r.w = ee_elem(v.w, m);
        __builtin_nontemporal_store(r, &o4[i]);
    }
}

extern "C" void kernel_launch(void* const* d_in, const int* in_sizes, int n_in,
                              void* d_out, int out_size, void* d_ws, size_t ws_size,
                              hipStream_t stream) {
    // setup_inputs order: x [8192*256], edge_attr [262144*128],
    //                     weights [8192*8192], edge_vector [128]
    const float* weights     = (const float*)d_in[2];
    const float* edge_vector = (const float*)d_in[3];
    const int ev_n = in_sizes[3];

    float* mean_ws = (float*)d_ws;      // d_ws re-poisoned every call; we rewrite it
    float* out = (float*)d_out;

    ee_mean_kernel<<<1, 64, 0, stream>>>(edge_vector, mean_ws, ev_n);

    long long n4 = (long long)out_size / 4;  // 8192*8192 divisible by 4
    const int block = 256;
    const int grid = 2048;  // grid-stride; ~32 float4 iters/thread
    EdgeEncoding_57655640982216_kernel<<<grid, block, 0, stream>>>(
        weights, mean_ws, out, n4);
}